// Round 11
// baseline (70.396 us; speedup 1.0000x reference)
//
#include <hip/hip_runtime.h>

typedef __attribute__((ext_vector_type(8))) short short8_t;      // 16B = MFMA frag
typedef _Float16 half8_t __attribute__((ext_vector_type(8)));
typedef _Float16 half2_t __attribute__((ext_vector_type(2)));
typedef __fp16 pk2_t __attribute__((ext_vector_type(2)));        // cvt_pkrtz native
typedef __attribute__((ext_vector_type(4))) int int4_t;
typedef __attribute__((ext_vector_type(4))) float float4_t;

#define MFMA16 __builtin_amdgcn_mfma_f32_16x16x32_f16
#define VMCNT(n) asm volatile("s_waitcnt vmcnt(" #n ")" ::: "memory")
#define SB0 __builtin_amdgcn_sched_barrier(0)
// asm-pinned global loads (compiler cannot sink/hoist across the VMCNT fences)
#define GLOADF4(dst, p) asm volatile("global_load_dwordx4 %0, %1, off" \
                                     : "=&v"(dst) : "v"(p) : "memory")
#define GLOADS8(dst, p) asm volatile("global_load_dwordx4 %0, %1, off" \
                                     : "=&v"(dst) : "v"(p) : "memory")

constexpr int BB   = 4;
constexpr int LL   = 2048;
constexpr int DM   = 1024;
constexpr int DK   = 128;
constexpr int MTOT = BB * LL;     // 8192
constexpr int MC   = 4;
constexpr float INV2PI = 0.15915494309189535f;

__device__ __forceinline__ void gload16(const void* g, void* l) {
    __builtin_amdgcn_global_load_lds(
        (const __attribute__((address_space(1))) void*)g,
        (__attribute__((address_space(3))) void*)l, 16, 0, 0);
}
__device__ __forceinline__ int pkrtz_i32(float a, float b) {
    pk2_t p = __builtin_amdgcn_cvt_pkrtz(a, b);
    return __builtin_bit_cast(int, p);
}

// ---------------------------------------------------------------------------
// K0: W [1024 k][128 n] f32 -> fragment-major W^T fp16 image.
// Per kc (64-k chunk): [cbt 8][s 8][cc 16][e 8]; n=cbt*16+cc,
// k = (s>>2)*32 + (s&3)*8 + e.  grid (16 kc, 3 arr).
// ---------------------------------------------------------------------------
__global__ __launch_bounds__(256) void k0_wsplit(
        const float* __restrict__ wq, const float* __restrict__ wk,
        const float* __restrict__ wv,
        _Float16* __restrict__ wq6, _Float16* __restrict__ wk6,
        _Float16* __restrict__ wv6) {
    int kc = blockIdx.x, a = blockIdx.y;
    const float* w = (a == 0) ? wq : (a == 1) ? wk : wv;
    _Float16* dst = (a == 0) ? wq6 : (a == 1) ? wk6 : wv6;
    __shared__ float tile[64 * 132];
    int t = threadIdx.x;
#pragma unroll
    for (int j = 0; j < 8; ++j) {
        int idx4 = t + j * 256;
        int kr = idx4 >> 5, n4 = idx4 & 31;
        *(float4_t*)(&tile[kr * 132 + n4 * 4]) =
            *(const float4_t*)(w + (size_t)(kc * 64 + kr) * DK + n4 * 4);
    }
    __syncthreads();
#pragma unroll
    for (int sw = 0; sw < 4; ++sw) {
        int ch = t + sw * 256;
        int cbt = ch >> 7, s = (ch >> 4) & 7, cc = ch & 15;
        int kb = (s >> 2) * 32 + (s & 3) * 8;
        int n = cbt * 16 + cc;
        half8_t h;
#pragma unroll
        for (int e = 0; e < 8; ++e) h[e] = (_Float16)tile[(kb + e) * 132 + n];
        *(half8_t*)(dst + (size_t)kc * 8192 + ch * 8) = h;
    }
}

// ---------------------------------------------------------------------------
// K1 v9: QKV projection, ZERO LDS / ZERO BARRIERS. BM=64, grid (128 mt, 3 grp),
// 4 waves (2Mx2N), wave tile 32r x 64c (rf=2, cf=4). A direct from x (f32,
// cvt in-reg), B direct from fp16 W images (L2). E/O named-register pipeline,
// asm-pinned loads + counted vmcnt + sched_barrier(0).
// ---------------------------------------------------------------------------
__global__ __launch_bounds__(256) void k1_proj(
        const float* __restrict__ x,
        const float* __restrict__ bq, const float* __restrict__ bk,
        const float* __restrict__ bv,
        const _Float16* __restrict__ wq6, const _Float16* __restrict__ wk6,
        const _Float16* __restrict__ wv6,
        _Float16* __restrict__ qim, _Float16* __restrict__ kim,
        _Float16* __restrict__ vim) {
    int mt = blockIdx.x, grp = blockIdx.y;
    int rowbase = mt * 64;
    int t = threadIdx.x, lane = t & 63, wid = t >> 6;
    int cc = lane & 15, g = lane >> 4;
    int wrow = (wid >> 1) * 32, wcol = (wid & 1) * 64;
    const _Float16* W6 = (grp == 0) ? wq6 : (grp == 1) ? wk6 : wv6;

    float4_t acc[2][4];
#pragma unroll
    for (int rf = 0; rf < 2; ++rf)
#pragma unroll
        for (int cf = 0; cf < 4; ++cf) acc[rf][cf] = (float4_t){0.f, 0.f, 0.f, 0.f};

    const float* pA[2];
#pragma unroll
    for (int rf = 0; rf < 2; ++rf)
        pA[rf] = x + (size_t)(rowbase + wrow + rf * 16 + cc) * DM + g * 8;
    const _Float16* pB[4];
#pragma unroll
    for (int cf = 0; cf < 4; ++cf)
        pB[cf] = W6 + ((wid & 1) * 4 + cf) * 1024 + g * 128 + cc * 8;

    float4_t AE[2][2], AO[2][2];
    short8_t BE[4], BO[4];

    auto issueSlice = [&](int u, float4_t (&A)[2][2], short8_t (&B)[4]) {
#pragma unroll
        for (int rf = 0; rf < 2; ++rf) {
            const float* p = pA[rf] + u * 32;
            GLOADF4(A[rf][0], p);
            GLOADF4(A[rf][1], p + 4);
        }
#pragma unroll
        for (int cf = 0; cf < 4; ++cf) {
            const _Float16* p = pB[cf] + (u >> 1) * 8192 + (u & 1) * 512;
            GLOADS8(B[cf], p);
        }
    };
    auto computeAcc = [&](float4_t (&A)[2][2], short8_t (&B)[4]) {
        half8_t ah[2];
#pragma unroll
        for (int rf = 0; rf < 2; ++rf) {
            int4_t iv;
#pragma unroll
            for (int j = 0; j < 4; ++j)
                iv[j] = pkrtz_i32(A[rf][j >> 1][(j & 1) * 2],
                                  A[rf][j >> 1][(j & 1) * 2 + 1]);
            ah[rf] = __builtin_bit_cast(half8_t, iv);
        }
#pragma unroll
        for (int cf = 0; cf < 4; ++cf) {
            half8_t bh = __builtin_bit_cast(half8_t, B[cf]);
#pragma unroll
            for (int rf = 0; rf < 2; ++rf)
                acc[rf][cf] = MFMA16(ah[rf], bh, acc[rf][cf], 0, 0, 0);
        }
    };

    issueSlice(0, AE, BE);
    issueSlice(1, AO, BO);
#pragma unroll 1
    for (int u = 0; u < 32; u += 2) {
        VMCNT(8); SB0;                 // E(u) landed; O(u+1)'s 8 still in flight
        computeAcc(AE, BE);
        if (u + 2 < 32) issueSlice(u + 2, AE, BE);
        if (u < 30) { VMCNT(8); } else { VMCNT(0); }
        SB0;                           // O(u+1) landed
        computeAcc(AO, BO);
        if (u + 3 < 32) issueSlice(u + 3, AO, BO);
    }

    // epilogue: bias + scatter into fragment-major fp16 images
    const float* bias = (grp == 0) ? bq : (grp == 1) ? bk : bv;
#pragma unroll
    for (int rf = 0; rf < 2; ++rf)
#pragma unroll
        for (int cf = 0; cf < 4; ++cf) {
            int c = wcol + cf * 16 + cc;
            float bv_ = bias[c];
#pragma unroll
            for (int i = 0; i < 4; ++i) {
                int r = rowbase + wrow + rf * 16 + g * 4 + i;
                float v = acc[rf][cf][i] + bv_;
                if (grp == 0) {
                    size_t o = (size_t)(r >> 4) * 2048 + (c >> 5) * 512 +
                               ((c >> 3) & 3) * 128 + (r & 15) * 8 + (c & 7);
                    qim[o] = (_Float16)v;
                } else if (grp == 1) {
                    size_t o = (size_t)(r >> 5) * 4096 + ((r >> 4) & 1) * 2048 +
                               (c >> 5) * 512 + ((c >> 3) & 3) * 128 +
                               (r & 15) * 8 + (c & 7);
                    kim[o] = (_Float16)v;
                } else {
                    size_t o = (size_t)(r >> 5) * 4096 + (c >> 4) * 512 +
                               ((r >> 3) & 3) * 128 + (c & 15) * 8 + (r & 7);
                    vim[o] = (_Float16)v;
                }
            }
        }
}

// ---------------------------------------------------------------------------
// K2 v7: out_partial = cos(Q K^T) V. grid (MC=4, L/64, B); 4 waves, 16 q-rows;
// KVBLK=64, 8 steps, 2-phase double buffer. SWAPPED QK^T (mfma(K,Q)) so each
// lane's S values are m-consecutive -> P stored via packed b32 writes.
// ---------------------------------------------------------------------------
__global__ __launch_bounds__(256, 2) void k2_attn(
        const _Float16* __restrict__ qim, const _Float16* __restrict__ kim,
        const _Float16* __restrict__ vim, float* __restrict__ part) {
    int mc = blockIdx.x, qt = blockIdx.y, b = blockIdx.z;
    int t = threadIdx.x, lane = t & 63, wid = t >> 6;
    int cc = lane & 15, g = lane >> 4;

    __shared__ __attribute__((aligned(16))) _Float16 kb[2][8192];
    __shared__ __attribute__((aligned(16))) _Float16 vb[2][8192];
    __shared__ __attribute__((aligned(16))) _Float16 ps[4][1024];

    int qrow = b * LL + qt * 64 + wid * 16;
    const _Float16* qb_ = qim + (size_t)(qrow >> 4) * 2048;
    half8_t qf[4];
#pragma unroll
    for (int s = 0; s < 4; ++s)
        qf[s] = *(const half8_t*)(qb_ + s * 512 + g * 128 + cc * 8);

    float4_t o[8];
#pragma unroll
    for (int cf = 0; cf < 8; ++cf) o[cf] = (float4_t){0.f, 0.f, 0.f, 0.f};

    int tbase = b * 64 + mc * 16;

    auto stageKV = [&](int mi, int buf) {
        const _Float16* ks = kim + (size_t)(tbase + mi * 2) * 4096;
        const _Float16* vs = vim + (size_t)(tbase + mi * 2) * 4096;
#pragma unroll
        for (int i = 0; i < 4; ++i) {
            gload16(ks + i * 2048 + t * 8, (char*)kb[buf] + i * 4096 + wid * 1024);
            gload16(vs + i * 2048 + t * 8, (char*)vb[buf] + i * 4096 + wid * 1024);
        }
    };

    stageKV(0, 0);
    __syncthreads();

#pragma unroll 1
    for (int mi = 0; mi < 8; ++mi) {
        int cb = mi & 1, nb = cb ^ 1;
        if (mi < 7) stageKV(mi + 1, nb);
        // ---- S^T = K Q^T (swapped): lane holds q=cc, m = cf*16 + g*4 + i
        float4_t sa[4];
#pragma unroll
        for (int cf = 0; cf < 4; ++cf) sa[cf] = (float4_t){0.f, 0.f, 0.f, 0.f};
#pragma unroll
        for (int cf = 0; cf < 4; ++cf)
#pragma unroll
            for (int s = 0; s < 4; ++s) {
                half8_t kf = *(const half8_t*)(kb[cb] + cf * 2048 + s * 512 +
                                               g * 128 + cc * 8);
                sa[cf] = MFMA16(kf, qf[s], sa[cf], 0, 0, 0);
            }
        // ---- P = cos(S) -> packed b32 writes, fragment-major [m>>3][q][m&7]
        // lane's m-values: m = cf*16 + g*4 + i; q = cc.
        // dst short addr: (m>>3)*128 + q*8 + (m&7)  -> for fixed cf, i=0..3
        // consecutive (m&7 = g*4+i within 8 when g even/odd pairs) -> 2x b32.
#pragma unroll
        for (int cf = 0; cf < 4; ++cf) {
            float cv[4];
#pragma unroll
            for (int i = 0; i < 4; ++i) {
                float rv = sa[cf][i] * INV2PI;
                rv = rv - floorf(rv);
                asm volatile("v_cos_f32 %0, %1" : "=v"(cv[i]) : "v"(rv));
            }
            int p0 = pkrtz_i32(cv[0], cv[1]);
            int p1 = pkrtz_i32(cv[2], cv[3]);
            int base = (2 * cf + (g >> 1)) * 128 + cc * 8 + (g & 1) * 4;
            *(int*)(&ps[wid][base])     = p0;
            *(int*)(&ps[wid][base + 2]) = p1;
        }
        // ---- out += P @ V
#pragma unroll
        for (int ksv = 0; ksv < 2; ++ksv) {
            half8_t pa = *(const half8_t*)(&ps[wid][(ksv * 4 + g) * 128 + cc * 8]);
#pragma unroll
            for (int cf = 0; cf < 8; ++cf) {
                half8_t vbf = *(const half8_t*)(vb[cb] + ksv * 4096 + cf * 512 +
                                                g * 128 + cc * 8);
                o[cf] = MFMA16(pa, vbf, o[cf], 0, 0, 0);
            }
        }
        __syncthreads();
    }
    float* pp = part + ((size_t)(mc * BB + b) * LL + qt * 64 + wid * 16) * DK;
#pragma unroll
    for (int cf = 0; cf < 8; ++cf)
#pragma unroll
        for (int i = 0; i < 4; ++i)
            pp[(g * 4 + i) * DK + cf * 16 + cc] = o[cf][i];
}

// ---------------------------------------------------------------------------
// K3: out = sum of MC partials
// ---------------------------------------------------------------------------
__global__ __launch_bounds__(256) void k3_reduce(const float4_t* __restrict__ part,
                                                 float4_t* __restrict__ out) {
    constexpr int NT4 = MTOT * DK / 4;
    int idx = blockIdx.x * 256 + threadIdx.x;
    float4_t s = part[idx];
#pragma unroll
    for (int c = 1; c < MC; ++c) s += part[idx + (size_t)c * NT4];
    out[idx] = s;
}

// ---------------------------------------------------------------------------
extern "C" void kernel_launch(void* const* d_in, const int* in_sizes, int n_in,
                              void* d_out, int out_size, void* d_ws, size_t ws_size,
                              hipStream_t stream) {
    const float* x  = (const float*)d_in[0];
    const float* Wq = (const float*)d_in[1];
    const float* bq = (const float*)d_in[2];
    const float* Wk = (const float*)d_in[3];
    const float* bk = (const float*)d_in[4];
    const float* Wv = (const float*)d_in[5];
    const float* bv = (const float*)d_in[6];

    char* ws = (char*)d_ws;
    size_t off = 0;
    auto alloc = [&](size_t bytes) -> char* {
        char* p = ws + off;
        off += (bytes + 255) & ~(size_t)255;
        return p;
    };
    _Float16* wq6 = (_Float16*)alloc((size_t)DK * DM * 2);
    _Float16* wk6 = (_Float16*)alloc((size_t)DK * DM * 2);
    _Float16* wv6 = (_Float16*)alloc((size_t)DK * DM * 2);
    _Float16* qim = (_Float16*)alloc((size_t)MTOT * DK * 2);
    _Float16* kim = (_Float16*)alloc((size_t)MTOT * DK * 2);
    _Float16* vim = (_Float16*)alloc((size_t)MTOT * DK * 2);
    float* part = (float*)alloc((size_t)MC * MTOT * DK * 4);

    k0_wsplit<<<dim3(16, 3), 256, 0, stream>>>(Wq, Wk, Wv, wq6, wk6, wv6);
    k1_proj<<<dim3(MTOT / 64, 3), 256, 0, stream>>>(x, bq, bk, bv,
                                                    wq6, wk6, wv6, qim, kim, vim);
    k2_attn<<<dim3(MC, LL / 64, BB), 256, 0, stream>>>(qim, kim, vim, part);
    k3_reduce<<<(MTOT * DK / 4) / 256, 256, 0, stream>>>((const float4_t*)part,
                                                         (float4_t*)d_out);
}

// Round 12
// 54.051 us; speedup vs baseline: 1.3024x; 1.3024x over previous
//
#include <hip/hip_runtime.h>

typedef _Float16 half8_t __attribute__((ext_vector_type(8)));
typedef _Float16 half2_t __attribute__((ext_vector_type(2)));
typedef __attribute__((ext_vector_type(4))) float float4_t;

#define MFMA16 __builtin_amdgcn_mfma_f32_16x16x32_f16

constexpr int BB   = 4;
constexpr int LL   = 2048;
constexpr int DM   = 1024;
constexpr int DK   = 128;
constexpr int MTOT = BB * LL;     // 8192
constexpr int MC   = 4;
constexpr float INV2PI = 0.15915494309189535f;

__device__ __forceinline__ void gload16(const void* g, void* l) {
    __builtin_amdgcn_global_load_lds(
        (const __attribute__((address_space(1))) void*)g,
        (__attribute__((address_space(3))) void*)l, 16, 0, 0);
}

// ---------------------------------------------------------------------------
// K0: W [1024 k][128 n] f32 -> fragment-major W^T fp16 image.
// Per kc (64-k chunk): [cbt 8][s 8][cc 16][e 8]; n=cbt*16+cc,
// k = (s>>2)*32 + (s&3)*8 + e.  grid (16 kc, 3 arr).
// ---------------------------------------------------------------------------
__global__ __launch_bounds__(256) void k0_wsplit(
        const float* __restrict__ wq, const float* __restrict__ wk,
        const float* __restrict__ wv,
        _Float16* __restrict__ wq6, _Float16* __restrict__ wk6,
        _Float16* __restrict__ wv6) {
    int kc = blockIdx.x, a = blockIdx.y;
    const float* w = (a == 0) ? wq : (a == 1) ? wk : wv;
    _Float16* dst = (a == 0) ? wq6 : (a == 1) ? wk6 : wv6;
    __shared__ float tile[64 * 132];
    int t = threadIdx.x;
#pragma unroll
    for (int j = 0; j < 8; ++j) {
        int idx4 = t + j * 256;
        int kr = idx4 >> 5, n4 = idx4 & 31;
        *(float4_t*)(&tile[kr * 132 + n4 * 4]) =
            *(const float4_t*)(w + (size_t)(kc * 64 + kr) * DK + n4 * 4);
    }
    __syncthreads();
#pragma unroll
    for (int sw = 0; sw < 4; ++sw) {
        int ch = t + sw * 256;
        int cbt = ch >> 7, s = (ch >> 4) & 7, cc = ch & 15;
        int kb = (s >> 2) * 32 + (s & 3) * 8;
        int n = cbt * 16 + cc;
        half8_t h;
#pragma unroll
        for (int e = 0; e < 8; ++e) h[e] = (_Float16)tile[(kb + e) * 132 + n];
        *(half8_t*)(dst + (size_t)kc * 8192 + ch * 8) = h;
    }
}

// ---------------------------------------------------------------------------
// K1 v10: QKV projection. BM=64, BK=64; grid (128 mt, 3 grp); 4 waves
// (2M x 2N), wave tile 32r x 64c (rf=2, cf=4): 16 MFMAs per 12 ds_read_b128.
// R9-proven 2-phase: stage(k+1) -> compute(k) -> one __syncthreads.
// LDS 50KB. All converts RNE.
// ---------------------------------------------------------------------------
__global__ __launch_bounds__(256) void k1_proj(
        const float* __restrict__ x,
        const float* __restrict__ bq, const float* __restrict__ bk,
        const float* __restrict__ bv,
        const _Float16* __restrict__ wq6, const _Float16* __restrict__ wk6,
        const _Float16* __restrict__ wv6,
        _Float16* __restrict__ qim, _Float16* __restrict__ kim,
        _Float16* __restrict__ vim) {
    int mt = blockIdx.x, grp = blockIdx.y;
    int rowbase = mt * 64;
    __shared__ __attribute__((aligned(16))) _Float16 xs[2][64 * 72];  // 9.2KB ea
    __shared__ __attribute__((aligned(16))) _Float16 wsm[2][8192];    // 16KB ea

    int t = threadIdx.x, lane = t & 63, wid = t >> 6;
    int cc = lane & 15, g = lane >> 4;
    int wr = (wid >> 1) * 32;          // wave row offset
    int wcN = wid & 1;                 // wave col half (64 cols)
    const _Float16* W6 = (grp == 0) ? wq6 : (grp == 1) ? wk6 : wv6;

    float4_t acc[2][4];
#pragma unroll
    for (int rf = 0; rf < 2; ++rf)
#pragma unroll
        for (int cf = 0; cf < 4; ++cf) acc[rf][cf] = (float4_t){0.f, 0.f, 0.f, 0.f};

    // x staging: 512 chunks of 8 halfs; thread t -> chunks t and t+256.
    // chunk ch: row = ch>>3 (0..63), c8 = ch&7; LDS addr row*72 + c8*8.
    int xrow = t >> 3, xc8 = t & 7;
    const float* xsrc0 = x + (size_t)(rowbase + xrow) * DM + xc8 * 8;
    const float* xsrc1 = xsrc0 + (size_t)32 * DM;       // row + 32
    int xo0 = xrow * 72 + xc8 * 8;
    int xo1 = (xrow + 32) * 72 + xc8 * 8;

    auto stageW = [&](int kc, int buf) {
        const _Float16* Wp = W6 + (size_t)kc * 8192;
#pragma unroll
        for (int i = 0; i < 4; ++i)
            gload16(Wp + i * 2048 + t * 8, (char*)wsm[buf] + i * 4096 + wid * 1024);
    };
    auto cvt8 = [&](float4_t f0, float4_t f1) {
        half8_t h;
#pragma unroll
        for (int e = 0; e < 4; ++e) { h[e] = (_Float16)f0[e]; h[e + 4] = (_Float16)f1[e]; }
        return h;
    };

    // prologue: x(0) + W(0) into buf 0
    {
        float4_t a0 = *(const float4_t*)(xsrc0), a1 = *(const float4_t*)(xsrc0 + 4);
        float4_t b0 = *(const float4_t*)(xsrc1), b1 = *(const float4_t*)(xsrc1 + 4);
        stageW(0, 0);
        *(half8_t*)(xs[0] + xo0) = cvt8(a0, a1);
        *(half8_t*)(xs[0] + xo1) = cvt8(b0, b1);
    }
    __syncthreads();

#pragma unroll 1
    for (int kc = 0; kc < 16; ++kc) {
        int cb = kc & 1, nb = cb ^ 1;
        bool more = (kc < 15);
        float4_t a0, a1, b0, b1;
        if (more) {
            a0 = *(const float4_t*)(xsrc0 + (size_t)(kc + 1) * 64);
            a1 = *(const float4_t*)(xsrc0 + (size_t)(kc + 1) * 64 + 4);
            b0 = *(const float4_t*)(xsrc1 + (size_t)(kc + 1) * 64);
            b1 = *(const float4_t*)(xsrc1 + (size_t)(kc + 1) * 64 + 4);
            stageW(kc + 1, nb);
        }
        // compute on cb: a 4 reads, b 8 reads, 16 MFMAs
        half8_t a_[2][2], b_[4][2];
#pragma unroll
        for (int rf = 0; rf < 2; ++rf)
#pragma unroll
            for (int ks = 0; ks < 2; ++ks)
                a_[rf][ks] = *(const half8_t*)(xs[cb] + (wr + rf * 16 + cc) * 72 +
                                               ks * 32 + g * 8);
#pragma unroll
        for (int cf = 0; cf < 4; ++cf)
#pragma unroll
            for (int ks = 0; ks < 2; ++ks)
                b_[cf][ks] = *(const half8_t*)(wsm[cb] + (wcN * 4 + cf) * 1024 +
                                               (ks * 4 + g) * 128 + cc * 8);
#pragma unroll
        for (int cf = 0; cf < 4; ++cf)
#pragma unroll
            for (int rf = 0; rf < 2; ++rf) {
                acc[rf][cf] = MFMA16(a_[rf][0], b_[cf][0], acc[rf][cf], 0, 0, 0);
                acc[rf][cf] = MFMA16(a_[rf][1], b_[cf][1], acc[rf][cf], 0, 0, 0);
            }
        if (more) {
            *(half8_t*)(xs[nb] + xo0) = cvt8(a0, a1);
            *(half8_t*)(xs[nb] + xo1) = cvt8(b0, b1);
        }
        __syncthreads();
    }

    // epilogue: bias + scatter into fragment-major fp16 images (RNE)
    const float* bias = (grp == 0) ? bq : (grp == 1) ? bk : bv;
#pragma unroll
    for (int rf = 0; rf < 2; ++rf)
#pragma unroll
        for (int cf = 0; cf < 4; ++cf) {
            int c = wcN * 64 + cf * 16 + cc;
            float bv_ = bias[c];
#pragma unroll
            for (int i = 0; i < 4; ++i) {
                int r = rowbase + wr + rf * 16 + g * 4 + i;
                float v = acc[rf][cf][i] + bv_;
                if (grp == 0) {
                    size_t o = (size_t)(r >> 4) * 2048 + (c >> 5) * 512 +
                               ((c >> 3) & 3) * 128 + (r & 15) * 8 + (c & 7);
                    qim[o] = (_Float16)v;
                } else if (grp == 1) {
                    size_t o = (size_t)(r >> 5) * 4096 + ((r >> 4) & 1) * 2048 +
                               (c >> 5) * 512 + ((c >> 3) & 3) * 128 +
                               (r & 15) * 8 + (c & 7);
                    kim[o] = (_Float16)v;
                } else {
                    size_t o = (size_t)(r >> 5) * 4096 + (c >> 4) * 512 +
                               ((r >> 3) & 3) * 128 + (c & 15) * 8 + (r & 7);
                    vim[o] = (_Float16)v;
                }
            }
        }
}

// ---------------------------------------------------------------------------
// K2 v8: out_partial = cos(Q K^T) V. grid (MC=4, L/128=16, B); 4 waves,
// 32 q-rows each (2 q-tiles): K/V fragments feed 2 MFMAs each.
// KVBLK=64, 8 steps, 2-phase double buffer. Swapped QK^T; RNE-packed P.
// LDS 80KB -> 1 block/CU; compute/step ~2400cyc >> L2 latency.
// ---------------------------------------------------------------------------
__global__ __launch_bounds__(256) void k2_attn(
        const _Float16* __restrict__ qim, const _Float16* __restrict__ kim,
        const _Float16* __restrict__ vim, float* __restrict__ part) {
    int mc = blockIdx.x, qt = blockIdx.y, b = blockIdx.z;
    int t = threadIdx.x, lane = t & 63, wid = t >> 6;
    int cc = lane & 15, g = lane >> 4;

    __shared__ __attribute__((aligned(16))) _Float16 kb[2][8192];   // 32KB
    __shared__ __attribute__((aligned(16))) _Float16 vb[2][8192];   // 32KB
    __shared__ __attribute__((aligned(16))) _Float16 ps[4][2][1024];// 16KB

    int qrow0 = b * LL + qt * 128 + wid * 32;
    half8_t qf[2][4];
#pragma unroll
    for (int qti = 0; qti < 2; ++qti) {
        const _Float16* qb_ = qim + (size_t)((qrow0 + qti * 16) >> 4) * 2048;
#pragma unroll
        for (int s = 0; s < 4; ++s)
            qf[qti][s] = *(const half8_t*)(qb_ + s * 512 + g * 128 + cc * 8);
    }
    float4_t o[2][8];
#pragma unroll
    for (int qti = 0; qti < 2; ++qti)
#pragma unroll
        for (int cf = 0; cf < 8; ++cf) o[qti][cf] = (float4_t){0.f, 0.f, 0.f, 0.f};

    int tbase = b * 64 + mc * 16;   // 32-row image-tile base

    auto stageKV = [&](int mi, int buf) {
        const _Float16* ks = kim + (size_t)(tbase + mi * 2) * 4096;
        const _Float16* vs = vim + (size_t)(tbase + mi * 2) * 4096;
#pragma unroll
        for (int i = 0; i < 4; ++i) {
            gload16(ks + i * 2048 + t * 8, (char*)kb[buf] + i * 4096 + wid * 1024);
            gload16(vs + i * 2048 + t * 8, (char*)vb[buf] + i * 4096 + wid * 1024);
        }
    };

    stageKV(0, 0);
    __syncthreads();

#pragma unroll 1
    for (int mi = 0; mi < 8; ++mi) {
        int cb = mi & 1, nb = cb ^ 1;
        if (mi < 7) stageKV(mi + 1, nb);
        // ---- S^T = K Q^T (swapped), K-frag shared across both q-tiles
        float4_t sa[2][4];
#pragma unroll
        for (int qti = 0; qti < 2; ++qti)
#pragma unroll
            for (int cf = 0; cf < 4; ++cf) sa[qti][cf] = (float4_t){0.f, 0.f, 0.f, 0.f};
#pragma unroll
        for (int cf = 0; cf < 4; ++cf)
#pragma unroll
            for (int s = 0; s < 4; ++s) {
                half8_t kf = *(const half8_t*)(kb[cb] + cf * 2048 + s * 512 +
                                               g * 128 + cc * 8);
                sa[0][cf] = MFMA16(kf, qf[0][s], sa[0][cf], 0, 0, 0);
                sa[1][cf] = MFMA16(kf, qf[1][s], sa[1][cf], 0, 0, 0);
            }
        // ---- P = cos(S), RNE pack, b32 writes; lane: q=cc, m=cf*16+g*4+i
#pragma unroll
        for (int qti = 0; qti < 2; ++qti)
#pragma unroll
            for (int cf = 0; cf < 4; ++cf) {
                float cv[4];
#pragma unroll
                for (int i = 0; i < 4; ++i) {
                    float rv = sa[qti][cf][i] * INV2PI;
                    rv = rv - floorf(rv);
                    asm volatile("v_cos_f32 %0, %1" : "=v"(cv[i]) : "v"(rv));
                }
                int base = (2 * cf + (g >> 1)) * 128 + cc * 8 + (g & 1) * 4;
                half2_t h01 = {(_Float16)cv[0], (_Float16)cv[1]};
                half2_t h23 = {(_Float16)cv[2], (_Float16)cv[3]};
                *(half2_t*)(&ps[wid][qti][base])     = h01;
                *(half2_t*)(&ps[wid][qti][base + 2]) = h23;
            }
        // ---- out += P @ V, V-frag shared across both q-tiles
#pragma unroll
        for (int ksv = 0; ksv < 2; ++ksv) {
            half8_t vf[8];
#pragma unroll
            for (int cf = 0; cf < 8; ++cf)
                vf[cf] = *(const half8_t*)(vb[cb] + ksv * 4096 + cf * 512 +
                                           g * 128 + cc * 8);
#pragma unroll
            for (int qti = 0; qti < 2; ++qti) {
                half8_t pa = *(const half8_t*)(&ps[wid][qti][(ksv * 4 + g) * 128 + cc * 8]);
#pragma unroll
                for (int cf = 0; cf < 8; ++cf)
                    o[qti][cf] = MFMA16(pa, vf[cf], o[qti][cf], 0, 0, 0);
            }
        }
        __syncthreads();
    }
    // store fp32 partials
#pragma unroll
    for (int qti = 0; qti < 2; ++qti) {
        float* pp = part + ((size_t)(mc * BB + b) * LL + qt * 128 + wid * 32 +
                            qti * 16) * DK;
#pragma unroll
        for (int cf = 0; cf < 8; ++cf)
#pragma unroll
            for (int i = 0; i < 4; ++i)
                pp[(g * 4 + i) * DK + cf * 16 + cc] = o[qti][cf][i];
    }
}

// ---------------------------------------------------------------------------
// K3: out = sum of MC partials
// ---------------------------------------------------------------------------
__global__ __launch_bounds__(256) void k3_reduce(const float4_t* __restrict__ part,
                                                 float4_t* __restrict__ out) {
    constexpr int NT4 = MTOT * DK / 4;
    int idx = blockIdx.x * 256 + threadIdx.x;
    float4_t s = part[idx];
#pragma unroll
    for (int c = 1; c < MC; ++c) s += part[idx + (size_t)c * NT4];
    out[idx] = s;
}

// ---------------------------------------------------------------------------
extern "C" void kernel_launch(void* const* d_in, const int* in_sizes, int n_in,
                              void* d_out, int out_size, void* d_ws, size_t ws_size,
                              hipStream_t stream) {
    const float* x  = (const float*)d_in[0];
    const float* Wq = (const float*)d_in[1];
    const float* bq = (const float*)d_in[2];
    const float* Wk = (const float*)d_in[3];
    const float* bk = (const float*)d_in[4];
    const float* Wv = (const float*)d_in[5];
    const float* bv = (const float*)d_in[6];

    char* ws = (char*)d_ws;
    size_t off = 0;
    auto alloc = [&](size_t bytes) -> char* {
        char* p = ws + off;
        off += (bytes + 255) & ~(size_t)255;
        return p;
    };
    _Float16* wq6 = (_Float16*)alloc((size_t)DK * DM * 2);
    _Float16* wk6 = (_Float16*)alloc((size_t)DK * DM * 2);
    _Float16* wv6 = (_Float16*)alloc((size_t)DK * DM * 2);
    _Float16* qim = (_Float16*)alloc((size_t)MTOT * DK * 2);
    _Float16* kim = (_Float16*)alloc((size_t)MTOT * DK * 2);
    _Float16* vim = (_Float16*)alloc((size_t)MTOT * DK * 2);
    float* part = (float*)alloc((size_t)MC * MTOT * DK * 4);

    k0_wsplit<<<dim3(16, 3), 256, 0, stream>>>(Wq, Wk, Wv, wq6, wk6, wv6);
    k1_proj<<<dim3(MTOT / 64, 3), 256, 0, stream>>>(x, bq, bk, bv,
                                                    wq6, wk6, wv6, qim, kim, vim);
    k2_attn<<<dim3(MC, LL / 128, BB), 256, 0, stream>>>(qim, kim, vim, part);
    k3_reduce<<<(MTOT * DK / 4) / 256, 256, 0, stream>>>((const float4_t*)part,
                                                         (float4_t*)d_out);
}

// Round 13
// 52.113 us; speedup vs baseline: 1.3508x; 1.0372x over previous
//
#include <hip/hip_runtime.h>

typedef _Float16 half8_t __attribute__((ext_vector_type(8)));
typedef _Float16 half4_t __attribute__((ext_vector_type(4)));
typedef __attribute__((ext_vector_type(4))) float float4_t;

#define MFMA16 __builtin_amdgcn_mfma_f32_16x16x32_f16

constexpr int BB   = 4;
constexpr int LL   = 2048;
constexpr int DM   = 1024;
constexpr int DK   = 128;
constexpr int MTOT = BB * LL;     // 8192
constexpr int MC   = 8;
constexpr float INV2PI = 0.15915494309189535f;

__device__ __forceinline__ void gload16(const void* g, void* l) {
    __builtin_amdgcn_global_load_lds(
        (const __attribute__((address_space(1))) void*)g,
        (__attribute__((address_space(3))) void*)l, 16, 0, 0);
}

// ---------------------------------------------------------------------------
// K0: W [1024 k][128 n] f32 -> fragment-major W^T fp16 image.
// Per kc (64-k chunk): [cbt 8][s 8][cc 16][e 8]; n=cbt*16+cc,
// k = (s>>2)*32 + (s&3)*8 + e.  grid (16 kc, 3 arr).
// ---------------------------------------------------------------------------
__global__ __launch_bounds__(256) void k0_wsplit(
        const float* __restrict__ wq, const float* __restrict__ wk,
        const float* __restrict__ wv,
        _Float16* __restrict__ wq6, _Float16* __restrict__ wk6,
        _Float16* __restrict__ wv6) {
    int kc = blockIdx.x, a = blockIdx.y;
    const float* w = (a == 0) ? wq : (a == 1) ? wk : wv;
    _Float16* dst = (a == 0) ? wq6 : (a == 1) ? wk6 : wv6;
    __shared__ float tile[64 * 132];
    int t = threadIdx.x;
#pragma unroll
    for (int j = 0; j < 8; ++j) {
        int idx4 = t + j * 256;
        int kr = idx4 >> 5, n4 = idx4 & 31;
        *(float4_t*)(&tile[kr * 132 + n4 * 4]) =
            *(const float4_t*)(w + (size_t)(kc * 64 + kr) * DK + n4 * 4);
    }
    __syncthreads();
#pragma unroll
    for (int sw = 0; sw < 4; ++sw) {
        int ch = t + sw * 256;
        int cbt = ch >> 7, s = (ch >> 4) & 7, cc = ch & 15;
        int kb = (s >> 2) * 32 + (s & 3) * 8;
        int n = cbt * 16 + cc;
        half8_t h;
#pragma unroll
        for (int e = 0; e < 8; ++e) h[e] = (_Float16)tile[(kb + e) * 132 + n];
        *(half8_t*)(dst + (size_t)kc * 8192 + ch * 8) = h;
    }
}

// ---------------------------------------------------------------------------
// K1 (R9-proven): QKV projection, fp16 single-term. BM=32, BK=64, BN=128;
// grid (256 mt, 3 grp); 4 waves, wave tile 32r x 32c. Simple 2-phase:
// stage(k+1) -> compute(k) -> one __syncthreads. LDS 41KB -> grid = 3/CU.
// ---------------------------------------------------------------------------
__global__ __launch_bounds__(256, 3) void k1_proj(
        const float* __restrict__ x,
        const float* __restrict__ bq, const float* __restrict__ bk,
        const float* __restrict__ bv,
        const _Float16* __restrict__ wq6, const _Float16* __restrict__ wk6,
        const _Float16* __restrict__ wv6,
        _Float16* __restrict__ qim, _Float16* __restrict__ kim,
        _Float16* __restrict__ vim) {
    int mt = blockIdx.x, grp = blockIdx.y;
    int rowbase = mt * 32;
    __shared__ __attribute__((aligned(16))) _Float16 xs[2][32 * 72];  // 4.5KB ea
    __shared__ __attribute__((aligned(16))) _Float16 wsm[2][8192];    // 16KB ea

    int t = threadIdx.x, lane = t & 63, wid = t >> 6;
    int cc = lane & 15, g = lane >> 4;
    const _Float16* W6 = (grp == 0) ? wq6 : (grp == 1) ? wk6 : wv6;

    float4_t acc[2][2];
#pragma unroll
    for (int rf = 0; rf < 2; ++rf)
#pragma unroll
        for (int cf = 0; cf < 2; ++cf) acc[rf][cf] = (float4_t){0.f, 0.f, 0.f, 0.f};

    int xr = t >> 3, xc8 = t & 7;
    const float* xsrc = x + (size_t)(rowbase + xr) * DM + xc8 * 8;
    int xoff = xr * 72 + xc8 * 8;

    auto stageW = [&](int kc, int buf) {
        const _Float16* Wp = W6 + (size_t)kc * 8192;
#pragma unroll
        for (int i = 0; i < 4; ++i)
            gload16(Wp + i * 2048 + t * 8, (char*)wsm[buf] + i * 4096 + wid * 1024);
    };
    auto cvt8 = [&](float4_t f0, float4_t f1) {
        half8_t h;
#pragma unroll
        for (int e = 0; e < 4; ++e) { h[e] = (_Float16)f0[e]; h[e + 4] = (_Float16)f1[e]; }
        return h;
    };

    {
        float4_t f0 = *(const float4_t*)(xsrc);
        float4_t f1 = *(const float4_t*)(xsrc + 4);
        stageW(0, 0);
        *(half8_t*)(xs[0] + xoff) = cvt8(f0, f1);
    }
    __syncthreads();

#pragma unroll 1
    for (int kc = 0; kc < 16; ++kc) {
        int cb = kc & 1, nb = cb ^ 1;
        bool more = (kc < 15);
        float4_t f0, f1;
        if (more) {
            f0 = *(const float4_t*)(xsrc + (size_t)(kc + 1) * 64);
            f1 = *(const float4_t*)(xsrc + (size_t)(kc + 1) * 64 + 4);
            stageW(kc + 1, nb);
        }
        half8_t a_[2][2], b_[2][2];
#pragma unroll
        for (int rf = 0; rf < 2; ++rf)
#pragma unroll
            for (int ks = 0; ks < 2; ++ks)
                a_[rf][ks] = *(const half8_t*)(xs[cb] + (rf * 16 + cc) * 72 + ks * 32 + g * 8);
#pragma unroll
        for (int cf = 0; cf < 2; ++cf)
#pragma unroll
            for (int ks = 0; ks < 2; ++ks)
                b_[cf][ks] = *(const half8_t*)(wsm[cb] + (wid * 2 + cf) * 1024 +
                                               (ks * 4 + g) * 128 + cc * 8);
#pragma unroll
        for (int cf = 0; cf < 2; ++cf)
#pragma unroll
            for (int rf = 0; rf < 2; ++rf) {
                acc[rf][cf] = MFMA16(a_[rf][0], b_[cf][0], acc[rf][cf], 0, 0, 0);
                acc[rf][cf] = MFMA16(a_[rf][1], b_[cf][1], acc[rf][cf], 0, 0, 0);
            }
        if (more) *(half8_t*)(xs[nb] + xoff) = cvt8(f0, f1);
        __syncthreads();
    }

    const float* bias = (grp == 0) ? bq : (grp == 1) ? bk : bv;
#pragma unroll
    for (int rf = 0; rf < 2; ++rf)
#pragma unroll
        for (int cf = 0; cf < 2; ++cf) {
            int c = wid * 32 + cf * 16 + cc;
            float bv_ = bias[c];
#pragma unroll
            for (int i = 0; i < 4; ++i) {
                int r = rowbase + rf * 16 + g * 4 + i;
                float v = acc[rf][cf][i] + bv_;
                if (grp == 0) {
                    size_t o = (size_t)(r >> 4) * 2048 + (c >> 5) * 512 +
                               ((c >> 3) & 3) * 128 + (r & 15) * 8 + (c & 7);
                    qim[o] = (_Float16)v;
                } else if (grp == 1) {
                    size_t o = (size_t)(r >> 5) * 4096 + ((r >> 4) & 1) * 2048 +
                               (c >> 5) * 512 + ((c >> 3) & 3) * 128 +
                               (r & 15) * 8 + (c & 7);
                    kim[o] = (_Float16)v;
                } else {
                    size_t o = (size_t)(r >> 5) * 4096 + (c >> 4) * 512 +
                               ((r >> 3) & 3) * 128 + (c & 15) * 8 + (r & 7);
                    vim[o] = (_Float16)v;
                }
            }
        }
}

// ---------------------------------------------------------------------------
// K2 v9: out_partial = cos(Q K^T) V. grid (MC=8, L/128=16, B) = 512 blocks
// (2 blocks/CU). 4 waves, 32 q-rows each (2 q-tiles). KVBLK=32 (1 image
// tile/step), 8 steps, 2-phase double buffer. LDS 40KB (4-block capacity).
// Swapped QK^T; K/V frags feed 2 MFMAs each; P-writes are single b64.
// ---------------------------------------------------------------------------
__global__ __launch_bounds__(256) void k2_attn(
        const _Float16* __restrict__ qim, const _Float16* __restrict__ kim,
        const _Float16* __restrict__ vim, float* __restrict__ part) {
    int mc = blockIdx.x, qt = blockIdx.y, b = blockIdx.z;
    int t = threadIdx.x, lane = t & 63, wid = t >> 6;
    int cc = lane & 15, g = lane >> 4;

    __shared__ __attribute__((aligned(16))) _Float16 kb[2][4096];   // 8KB ea
    __shared__ __attribute__((aligned(16))) _Float16 vb[2][4096];   // 8KB ea
    __shared__ __attribute__((aligned(16))) _Float16 ps[4][2][512]; // 8KB

    int qrow0 = b * LL + qt * 128 + wid * 32;
    half8_t qf[2][4];
#pragma unroll
    for (int qti = 0; qti < 2; ++qti) {
        const _Float16* qb_ = qim + (size_t)((qrow0 + qti * 16) >> 4) * 2048;
#pragma unroll
        for (int s = 0; s < 4; ++s)
            qf[qti][s] = *(const half8_t*)(qb_ + s * 512 + g * 128 + cc * 8);
    }
    float4_t o[2][8];
#pragma unroll
    for (int qti = 0; qti < 2; ++qti)
#pragma unroll
        for (int cf = 0; cf < 8; ++cf) o[qti][cf] = (float4_t){0.f, 0.f, 0.f, 0.f};

    int tbase = b * 64 + mc * 8;    // 32-row image-tile base (8 tiles/chunk)

    auto stageKV = [&](int mi, int buf) {
        const _Float16* ks = kim + (size_t)(tbase + mi) * 4096;
        const _Float16* vs = vim + (size_t)(tbase + mi) * 4096;
#pragma unroll
        for (int i = 0; i < 2; ++i) {
            gload16(ks + i * 2048 + t * 8, (char*)kb[buf] + i * 4096 + wid * 1024);
            gload16(vs + i * 2048 + t * 8, (char*)vb[buf] + i * 4096 + wid * 1024);
        }
    };

    stageKV(0, 0);
    __syncthreads();

#pragma unroll 1
    for (int mi = 0; mi < 8; ++mi) {
        int cb = mi & 1, nb = cb ^ 1;
        if (mi < 7) stageKV(mi + 1, nb);
        // ---- S^T = K Q^T (swapped): lane holds q=cc, m = cf*16 + g*4 + i
        float4_t sa[2][2];
#pragma unroll
        for (int qti = 0; qti < 2; ++qti)
#pragma unroll
            for (int cf = 0; cf < 2; ++cf) sa[qti][cf] = (float4_t){0.f, 0.f, 0.f, 0.f};
#pragma unroll
        for (int cf = 0; cf < 2; ++cf)
#pragma unroll
            for (int s = 0; s < 4; ++s) {
                half8_t kf = *(const half8_t*)(kb[cb] + cf * 2048 + s * 512 +
                                               g * 128 + cc * 8);
                sa[0][cf] = MFMA16(kf, qf[0][s], sa[0][cf], 0, 0, 0);
                sa[1][cf] = MFMA16(kf, qf[1][s], sa[1][cf], 0, 0, 0);
            }
        // ---- P = cos(S) -> [m>>3][q][m&7]; i=0..3 contiguous -> one b64
#pragma unroll
        for (int qti = 0; qti < 2; ++qti)
#pragma unroll
            for (int cf = 0; cf < 2; ++cf) {
                half4_t h4;
#pragma unroll
                for (int i = 0; i < 4; ++i) {
                    float rv = sa[qti][cf][i] * INV2PI;
                    rv = rv - floorf(rv);
                    float cv;
                    asm volatile("v_cos_f32 %0, %1" : "=v"(cv) : "v"(rv));
                    h4[i] = (_Float16)cv;
                }
                int base = (cf * 2 + (g >> 1)) * 128 + cc * 8 + (g & 1) * 4;
                *(half4_t*)(&ps[wid][qti][base]) = h4;
            }
        // ---- out += P @ V (k=32, one MFMA per cf; V-frag shared across qti)
        half8_t pa0 = *(const half8_t*)(&ps[wid][0][g * 128 + cc * 8]);
        half8_t pa1 = *(const half8_t*)(&ps[wid][1][g * 128 + cc * 8]);
#pragma unroll
        for (int cf = 0; cf < 8; ++cf) {
            half8_t vf = *(const half8_t*)(vb[cb] + cf * 512 + g * 128 + cc * 8);
            o[0][cf] = MFMA16(pa0, vf, o[0][cf], 0, 0, 0);
            o[1][cf] = MFMA16(pa1, vf, o[1][cf], 0, 0, 0);
        }
        __syncthreads();
    }
    // store fp32 partials: layout [MC][B][L][DK]
#pragma unroll
    for (int qti = 0; qti < 2; ++qti) {
        float* pp = part + ((size_t)(mc * BB + b) * LL + qt * 128 + wid * 32 +
                            qti * 16) * DK;
#pragma unroll
        for (int cf = 0; cf < 8; ++cf)
#pragma unroll
            for (int i = 0; i < 4; ++i)
                pp[(g * 4 + i) * DK + cf * 16 + cc] = o[qti][cf][i];
    }
}

// ---------------------------------------------------------------------------
// K3: out = sum of MC partials
// ---------------------------------------------------------------------------
__global__ __launch_bounds__(256) void k3_reduce(const float4_t* __restrict__ part,
                                                 float4_t* __restrict__ out) {
    constexpr int NT4 = MTOT * DK / 4;
    int idx = blockIdx.x * 256 + threadIdx.x;
    float4_t s = part[idx];
#pragma unroll
    for (int c = 1; c < MC; ++c) s += part[idx + (size_t)c * NT4];
    out[idx] = s;
}

// ---------------------------------------------------------------------------
extern "C" void kernel_launch(void* const* d_in, const int* in_sizes, int n_in,
                              void* d_out, int out_size, void* d_ws, size_t ws_size,
                              hipStream_t stream) {
    const float* x  = (const float*)d_in[0];
    const float* Wq = (const float*)d_in[1];
    const float* bq = (const float*)d_in[2];
    const float* Wk = (const float*)d_in[3];
    const float* bk = (const float*)d_in[4];
    const float* Wv = (const float*)d_in[5];
    const float* bv = (const float*)d_in[6];

    char* ws = (char*)d_ws;
    size_t off = 0;
    auto alloc = [&](size_t bytes) -> char* {
        char* p = ws + off;
        off += (bytes + 255) & ~(size_t)255;
        return p;
    };
    _Float16* wq6 = (_Float16*)alloc((size_t)DK * DM * 2);
    _Float16* wk6 = (_Float16*)alloc((size_t)DK * DM * 2);
    _Float16* wv6 = (_Float16*)alloc((size_t)DK * DM * 2);
    _Float16* qim = (_Float16*)alloc((size_t)MTOT * DK * 2);
    _Float16* kim = (_Float16*)alloc((size_t)MTOT * DK * 2);
    _Float16* vim = (_Float16*)alloc((size_t)MTOT * DK * 2);
    float* part = (float*)alloc((size_t)MC * MTOT * DK * 4);

    k0_wsplit<<<dim3(16, 3), 256, 0, stream>>>(Wq, Wk, Wv, wq6, wk6, wv6);
    k1_proj<<<dim3(MTOT / 32, 3), 256, 0, stream>>>(x, bq, bk, bv,
                                                    wq6, wk6, wv6, qim, kim, vim);
    k2_attn<<<dim3(MC, LL / 128, BB), 256, 0, stream>>>(qim, kim, vim, part);
    k3_reduce<<<(MTOT * DK / 4) / 256, 256, 0, stream>>>((const float4_t*)part,
                                                         (float4_t*)d_out);
}

// Round 16
// 48.090 us; speedup vs baseline: 1.4638x; 1.0837x over previous
//
#include <hip/hip_runtime.h>

typedef _Float16 half8_t __attribute__((ext_vector_type(8)));
typedef _Float16 half4_t __attribute__((ext_vector_type(4)));
typedef __attribute__((ext_vector_type(4))) float float4_t;

#define MFMA16 __builtin_amdgcn_mfma_f32_16x16x32_f16

constexpr int BB   = 4;
constexpr int LL   = 2048;
constexpr int DM   = 1024;
constexpr int DK   = 128;
constexpr int MTOT = BB * LL;     // 8192
constexpr int MC   = 4;
constexpr float INV2PI = 0.15915494309189535f;

__device__ __forceinline__ void gload16(const void* g, void* l) {
    __builtin_amdgcn_global_load_lds(
        (const __attribute__((address_space(1))) void*)g,
        (__attribute__((address_space(3))) void*)l, 16, 0, 0);
}

// ---------------------------------------------------------------------------
// K0: W [1024 k][128 n] f32 -> fragment-major W^T fp16 image.
// Per kc (64-k chunk): [cbt 8][s 8][cc 16][e 8]; n=cbt*16+cc,
// k = (s>>2)*32 + (s&3)*8 + e.  grid (16 kc, 3 arr).
// ---------------------------------------------------------------------------
__global__ __launch_bounds__(256) void k0_wsplit(
        const float* __restrict__ wq, const float* __restrict__ wk,
        const float* __restrict__ wv,
        _Float16* __restrict__ wq6, _Float16* __restrict__ wk6,
        _Float16* __restrict__ wv6) {
    int kc = blockIdx.x, a = blockIdx.y;
    const float* w = (a == 0) ? wq : (a == 1) ? wk : wv;
    _Float16* dst = (a == 0) ? wq6 : (a == 1) ? wk6 : wv6;
    __shared__ float tile[64 * 132];
    int t = threadIdx.x;
#pragma unroll
    for (int j = 0; j < 8; ++j) {
        int idx4 = t + j * 256;
        int kr = idx4 >> 5, n4 = idx4 & 31;
        *(float4_t*)(&tile[kr * 132 + n4 * 4]) =
            *(const float4_t*)(w + (size_t)(kc * 64 + kr) * DK + n4 * 4);
    }
    __syncthreads();
#pragma unroll
    for (int sw = 0; sw < 4; ++sw) {
        int ch = t + sw * 256;
        int cbt = ch >> 7, s = (ch >> 4) & 7, cc = ch & 15;
        int kb = (s >> 2) * 32 + (s & 3) * 8;
        int n = cbt * 16 + cc;
        half8_t h;
#pragma unroll
        for (int e = 0; e < 8; ++e) h[e] = (_Float16)tile[(kb + e) * 132 + n];
        *(half8_t*)(dst + (size_t)kc * 8192 + ch * 8) = h;
    }
}

// ---------------------------------------------------------------------------
// K1 (R9-proven): QKV projection, fp16 single-term. BM=32, BK=64, BN=128;
// grid (256 mt, 3 grp); 4 waves, wave tile 32r x 32c. Simple 2-phase:
// stage(k+1) -> compute(k) -> one __syncthreads. LDS 41KB -> grid = 3/CU.
// ---------------------------------------------------------------------------
__global__ __launch_bounds__(256, 3) void k1_proj(
        const float* __restrict__ x,
        const float* __restrict__ bq, const float* __restrict__ bk,
        const float* __restrict__ bv,
        const _Float16* __restrict__ wq6, const _Float16* __restrict__ wk6,
        const _Float16* __restrict__ wv6,
        _Float16* __restrict__ qim, _Float16* __restrict__ kim,
        _Float16* __restrict__ vim) {
    int mt = blockIdx.x, grp = blockIdx.y;
    int rowbase = mt * 32;
    __shared__ __attribute__((aligned(16))) _Float16 xs[2][32 * 72];  // 4.5KB ea
    __shared__ __attribute__((aligned(16))) _Float16 wsm[2][8192];    // 16KB ea

    int t = threadIdx.x, lane = t & 63, wid = t >> 6;
    int cc = lane & 15, g = lane >> 4;
    const _Float16* W6 = (grp == 0) ? wq6 : (grp == 1) ? wk6 : wv6;

    float4_t acc[2][2];
#pragma unroll
    for (int rf = 0; rf < 2; ++rf)
#pragma unroll
        for (int cf = 0; cf < 2; ++cf) acc[rf][cf] = (float4_t){0.f, 0.f, 0.f, 0.f};

    int xr = t >> 3, xc8 = t & 7;
    const float* xsrc = x + (size_t)(rowbase + xr) * DM + xc8 * 8;
    int xoff = xr * 72 + xc8 * 8;

    auto stageW = [&](int kc, int buf) {
        const _Float16* Wp = W6 + (size_t)kc * 8192;
#pragma unroll
        for (int i = 0; i < 4; ++i)
            gload16(Wp + i * 2048 + t * 8, (char*)wsm[buf] + i * 4096 + wid * 1024);
    };
    auto cvt8 = [&](float4_t f0, float4_t f1) {
        half8_t h;
#pragma unroll
        for (int e = 0; e < 4; ++e) { h[e] = (_Float16)f0[e]; h[e + 4] = (_Float16)f1[e]; }
        return h;
    };

    {
        float4_t f0 = *(const float4_t*)(xsrc);
        float4_t f1 = *(const float4_t*)(xsrc + 4);
        stageW(0, 0);
        *(half8_t*)(xs[0] + xoff) = cvt8(f0, f1);
    }
    __syncthreads();

#pragma unroll 1
    for (int kc = 0; kc < 16; ++kc) {
        int cb = kc & 1, nb = cb ^ 1;
        bool more = (kc < 15);
        float4_t f0, f1;
        if (more) {
            f0 = *(const float4_t*)(xsrc + (size_t)(kc + 1) * 64);
            f1 = *(const float4_t*)(xsrc + (size_t)(kc + 1) * 64 + 4);
            stageW(kc + 1, nb);
        }
        half8_t a_[2][2], b_[2][2];
#pragma unroll
        for (int rf = 0; rf < 2; ++rf)
#pragma unroll
            for (int ks = 0; ks < 2; ++ks)
                a_[rf][ks] = *(const half8_t*)(xs[cb] + (rf * 16 + cc) * 72 + ks * 32 + g * 8);
#pragma unroll
        for (int cf = 0; cf < 2; ++cf)
#pragma unroll
            for (int ks = 0; ks < 2; ++ks)
                b_[cf][ks] = *(const half8_t*)(wsm[cb] + (wid * 2 + cf) * 1024 +
                                               (ks * 4 + g) * 128 + cc * 8);
#pragma unroll
        for (int cf = 0; cf < 2; ++cf)
#pragma unroll
            for (int rf = 0; rf < 2; ++rf) {
                acc[rf][cf] = MFMA16(a_[rf][0], b_[cf][0], acc[rf][cf], 0, 0, 0);
                acc[rf][cf] = MFMA16(a_[rf][1], b_[cf][1], acc[rf][cf], 0, 0, 0);
            }
        if (more) *(half8_t*)(xs[nb] + xoff) = cvt8(f0, f1);
        __syncthreads();
    }

    const float* bias = (grp == 0) ? bq : (grp == 1) ? bk : bv;
#pragma unroll
    for (int rf = 0; rf < 2; ++rf)
#pragma unroll
        for (int cf = 0; cf < 2; ++cf) {
            int c = wid * 32 + cf * 16 + cc;
            float bv_ = bias[c];
#pragma unroll
            for (int i = 0; i < 4; ++i) {
                int r = rowbase + rf * 16 + g * 4 + i;
                float v = acc[rf][cf][i] + bv_;
                if (grp == 0) {
                    size_t o = (size_t)(r >> 4) * 2048 + (c >> 5) * 512 +
                               ((c >> 3) & 3) * 128 + (r & 15) * 8 + (c & 7);
                    qim[o] = (_Float16)v;
                } else if (grp == 1) {
                    size_t o = (size_t)(r >> 5) * 4096 + ((r >> 4) & 1) * 2048 +
                               (c >> 5) * 512 + ((c >> 3) & 3) * 128 +
                               (r & 15) * 8 + (c & 7);
                    kim[o] = (_Float16)v;
                } else {
                    size_t o = (size_t)(r >> 5) * 4096 + (c >> 4) * 512 +
                               ((r >> 3) & 3) * 128 + (c & 15) * 8 + (r & 7);
                    vim[o] = (_Float16)v;
                }
            }
        }
}

// ---------------------------------------------------------------------------
// K2 v10: R9-v6 structure + swapped QK^T (R13-proven) + half4 P-writes +
// fp16 partial stores. grid (MC=4, L/64, B); 4 waves, 16 q-rows each;
// KVBLK=64, 8 steps, 2-phase double buffer. LDS 72KB -> 2 blocks/CU.
// ---------------------------------------------------------------------------
__global__ __launch_bounds__(256, 2) void k2_attn(
        const _Float16* __restrict__ qim, const _Float16* __restrict__ kim,
        const _Float16* __restrict__ vim, _Float16* __restrict__ part) {
    int mc = blockIdx.x, qt = blockIdx.y, b = blockIdx.z;
    int t = threadIdx.x, lane = t & 63, wid = t >> 6;
    int cc = lane & 15, g = lane >> 4;

    __shared__ __attribute__((aligned(16))) _Float16 kb[2][8192];   // 16KB ea
    __shared__ __attribute__((aligned(16))) _Float16 vb[2][8192];   // 16KB ea
    __shared__ __attribute__((aligned(16))) _Float16 ps[4][1024];   // per-wave P

    int qrow = b * LL + qt * 64 + wid * 16;
    const _Float16* qb_ = qim + (size_t)(qrow >> 4) * 2048;
    half8_t qf[4];
#pragma unroll
    for (int s = 0; s < 4; ++s)
        qf[s] = *(const half8_t*)(qb_ + s * 512 + g * 128 + cc * 8);

    float4_t o[8];
#pragma unroll
    for (int cf = 0; cf < 8; ++cf) o[cf] = (float4_t){0.f, 0.f, 0.f, 0.f};

    int tbase = b * 64 + mc * 16;   // 32-row tile index base

    auto stageKV = [&](int mi, int buf) {
        const _Float16* ks = kim + (size_t)(tbase + mi * 2) * 4096;
        const _Float16* vs = vim + (size_t)(tbase + mi * 2) * 4096;
#pragma unroll
        for (int i = 0; i < 4; ++i) {
            gload16(ks + i * 2048 + t * 8, (char*)kb[buf] + i * 4096 + wid * 1024);
            gload16(vs + i * 2048 + t * 8, (char*)vb[buf] + i * 4096 + wid * 1024);
        }
    };

    stageKV(0, 0);
    __syncthreads();

#pragma unroll 1
    for (int mi = 0; mi < 8; ++mi) {
        int cb = mi & 1, nb = cb ^ 1;
        if (mi < 7) stageKV(mi + 1, nb);
        // ---- S^T = K Q^T (swapped): lane holds q=cc, m = cf*16 + g*4 + i
        float4_t sa[4];
#pragma unroll
        for (int cf = 0; cf < 4; ++cf) sa[cf] = (float4_t){0.f, 0.f, 0.f, 0.f};
#pragma unroll
        for (int cf = 0; cf < 4; ++cf)
#pragma unroll
            for (int s = 0; s < 4; ++s) {
                half8_t kf = *(const half8_t*)(kb[cb] + cf * 2048 + s * 512 +
                                               g * 128 + cc * 8);
                sa[cf] = MFMA16(kf, qf[s], sa[cf], 0, 0, 0);
            }
        // ---- P = cos(S) -> [m>>3][q][m&7]; i=0..3 contiguous -> one b64
#pragma unroll
        for (int cf = 0; cf < 4; ++cf) {
            half4_t h4;
#pragma unroll
            for (int i = 0; i < 4; ++i) {
                float rv = sa[cf][i] * INV2PI;
                rv = rv - floorf(rv);
                float cv;
                asm volatile("v_cos_f32 %0, %1" : "=v"(cv) : "v"(rv));
                h4[i] = (_Float16)cv;
            }
            int base = (cf * 2 + (g >> 1)) * 128 + cc * 8 + (g & 1) * 4;
            *(half4_t*)(&ps[wid][base]) = h4;
        }
        // ---- out += P @ V
#pragma unroll
        for (int ksv = 0; ksv < 2; ++ksv) {
            half8_t pa = *(const half8_t*)(&ps[wid][(ksv * 4 + g) * 128 + cc * 8]);
#pragma unroll
            for (int cf = 0; cf < 8; ++cf) {
                half8_t vbf = *(const half8_t*)(vb[cb] + ksv * 4096 + cf * 512 +
                                                g * 128 + cc * 8);
                o[cf] = MFMA16(pa, vbf, o[cf], 0, 0, 0);
            }
        }
        __syncthreads();
    }
    // ---- store fp16 partials: layout [MC][B][L][DK]
    _Float16* pp = part + ((size_t)(mc * BB + b) * LL + qt * 64 + wid * 16) * DK;
#pragma unroll
    for (int cf = 0; cf < 8; ++cf)
#pragma unroll
        for (int i = 0; i < 4; ++i)
            pp[(g * 4 + i) * DK + cf * 16 + cc] = (_Float16)o[cf][i];
}

// ---------------------------------------------------------------------------
// K3: out = sum of MC fp16 partials (fp32 accumulate, fp32 out)
// ---------------------------------------------------------------------------
__global__ __launch_bounds__(256) void k3_reduce(const _Float16* __restrict__ part,
                                                 float4_t* __restrict__ out) {
    constexpr int NT8 = MTOT * DK / 8;   // 131072 8-elem units per chunk
    int idx = blockIdx.x * 256 + threadIdx.x;
    const half8_t* p = (const half8_t*)part;
    float s[8];
#pragma unroll
    for (int e = 0; e < 8; ++e) s[e] = 0.f;
#pragma unroll
    for (int c = 0; c < MC; ++c) {
        half8_t v = p[idx + (size_t)c * NT8];
#pragma unroll
        for (int e = 0; e < 8; ++e) s[e] += (float)v[e];
    }
    float4_t o0 = {s[0], s[1], s[2], s[3]};
    float4_t o1 = {s[4], s[5], s[6], s[7]};
    out[idx * 2]     = o0;
    out[idx * 2 + 1] = o1;
}

// ---------------------------------------------------------------------------
extern "C" void kernel_launch(void* const* d_in, const int* in_sizes, int n_in,
                              void* d_out, int out_size, void* d_ws, size_t ws_size,
                              hipStream_t stream) {
    const float* x  = (const float*)d_in[0];
    const float* Wq = (const float*)d_in[1];
    const float* bq = (const float*)d_in[2];
    const float* Wk = (const float*)d_in[3];
    const float* bk = (const float*)d_in[4];
    const float* Wv = (const float*)d_in[5];
    const float* bv = (const float*)d_in[6];

    char* ws = (char*)d_ws;
    size_t off = 0;
    auto alloc = [&](size_t bytes) -> char* {
        char* p = ws + off;
        off += (bytes + 255) & ~(size_t)255;
        return p;
    };
    _Float16* wq6 = (_Float16*)alloc((size_t)DK * DM * 2);
    _Float16* wk6 = (_Float16*)alloc((size_t)DK * DM * 2);
    _Float16* wv6 = (_Float16*)alloc((size_t)DK * DM * 2);
    _Float16* qim = (_Float16*)alloc((size_t)MTOT * DK * 2);
    _Float16* kim = (_Float16*)alloc((size_t)MTOT * DK * 2);
    _Float16* vim = (_Float16*)alloc((size_t)MTOT * DK * 2);
    _Float16* part = (_Float16*)alloc((size_t)MC * MTOT * DK * 2);

    k0_wsplit<<<dim3(16, 3), 256, 0, stream>>>(Wq, Wk, Wv, wq6, wk6, wv6);
    k1_proj<<<dim3(MTOT / 32, 3), 256, 0, stream>>>(x, bq, bk, bv,
                                                    wq6, wk6, wv6, qim, kim, vim);
    k2_attn<<<dim3(MC, LL / 64, BB), 256, 0, stream>>>(qim, kim, vim, part);
    k3_reduce<<<(MTOT * DK / 8) / 256, 256, 0, stream>>>(part, (float4_t*)d_out);
}